// Round 1
// baseline (4157.381 us; speedup 1.0000x reference)
//
#include <hip/hip_runtime.h>
#include <math.h>

#define B_SZ 64
#define T_IN 80
#define D_IN 4096
#define H_SZ 256
#define V_SZ 6144
#define L_DEC 30
#define G4 1024              // 4*H
#define SYMBASE (B_SZ * L_DEC * V_SZ)

// ---------------- transpose: in [R][C] -> out [C][R] ----------------
__global__ __launch_bounds__(256) void ktranspose(const float* __restrict__ in,
                                                  float* __restrict__ out,
                                                  int R, int C) {
    __shared__ float tile[32][33];
    int c0 = blockIdx.x * 32, r0 = blockIdx.y * 32;
    int tx = threadIdx.x, ty = threadIdx.y;  // block (32,8)
    for (int i = ty; i < 32; i += 8) {
        int r = r0 + i, c = c0 + tx;
        tile[i][tx] = (r < R && c < C) ? in[(size_t)r * C + c] : 0.f;
    }
    __syncthreads();
    for (int i = ty; i < 32; i += 8) {
        int c = c0 + i, r = r0 + tx;
        if (c < C && r < R) out[(size_t)c * R + r] = tile[tx][i];
    }
}

// ---------------- bias sums ----------------
__global__ void biasum(const float* a1, const float* b1, const float* a2, const float* b2,
                       float* o1, float* o2) {
    int i = blockIdx.x * 256 + threadIdx.x;
    if (i < G4) { o1[i] = a1[i] + b1[i]; o2[i] = a2[i] + b2[i]; }
}

// ---------------- init state ----------------
__global__ void init_state(float* h, float* c, int* sym) {
    int i = blockIdx.x * 256 + threadIdx.x;  // 64*256 = 16384
    h[i] = 0.f; c[i] = 0.f;
    if (i < B_SZ) sym[i] = 1;  // SOS
}

// ---------------- tiled fp32 GEMM: C[M][N] = A[M][K] * W[N][K]^T + bias[N] ----------------
// BM=BN=128, BK=16, 256 threads, 8x8 micro-tile
__global__ __launch_bounds__(256) void gemm_rr(const float* __restrict__ A,
                                               const float* __restrict__ W,
                                               const float* __restrict__ bias,
                                               float* __restrict__ C,
                                               int M, int N, int K) {
    __shared__ __align__(16) float As[16][128];
    __shared__ __align__(16) float Bs[16][128];
    const int tid = threadIdx.x;
    const int tx = tid & 15, ty = tid >> 4;
    const int m0 = blockIdx.y * 128, n0 = blockIdx.x * 128;

    const int a_m = tid >> 2;          // 0..63
    const int a_k = (tid & 3) * 4;     // 0,4,8,12
    const int b_n = tid >> 1;          // 0..127
    const int b_k = (tid & 1) * 8;     // 0,8

    float acc[8][8];
#pragma unroll
    for (int r = 0; r < 8; ++r)
#pragma unroll
        for (int cc = 0; cc < 8; ++cc) acc[r][cc] = 0.f;

    for (int k0 = 0; k0 < K; k0 += 16) {
        float4 av0 = *(const float4*)(A + (size_t)(m0 + a_m) * K + k0 + a_k);
        float4 av1 = *(const float4*)(A + (size_t)(m0 + a_m + 64) * K + k0 + a_k);
        float4 bv0 = *(const float4*)(W + (size_t)(n0 + b_n) * K + k0 + b_k);
        float4 bv1 = *(const float4*)(W + (size_t)(n0 + b_n) * K + k0 + b_k + 4);
        __syncthreads();
        As[a_k + 0][a_m] = av0.x; As[a_k + 1][a_m] = av0.y;
        As[a_k + 2][a_m] = av0.z; As[a_k + 3][a_m] = av0.w;
        As[a_k + 0][a_m + 64] = av1.x; As[a_k + 1][a_m + 64] = av1.y;
        As[a_k + 2][a_m + 64] = av1.z; As[a_k + 3][a_m + 64] = av1.w;
        Bs[b_k + 0][b_n] = bv0.x; Bs[b_k + 1][b_n] = bv0.y;
        Bs[b_k + 2][b_n] = bv0.z; Bs[b_k + 3][b_n] = bv0.w;
        Bs[b_k + 4][b_n] = bv1.x; Bs[b_k + 5][b_n] = bv1.y;
        Bs[b_k + 6][b_n] = bv1.z; Bs[b_k + 7][b_n] = bv1.w;
        __syncthreads();
#pragma unroll
        for (int kk = 0; kk < 16; ++kk) {
            const float4 a0 = *(const float4*)&As[kk][ty * 8];
            const float4 a1 = *(const float4*)&As[kk][ty * 8 + 4];
            const float4 b0 = *(const float4*)&Bs[kk][tx * 8];
            const float4 b1 = *(const float4*)&Bs[kk][tx * 8 + 4];
            const float ar[8] = {a0.x, a0.y, a0.z, a0.w, a1.x, a1.y, a1.z, a1.w};
            const float br[8] = {b0.x, b0.y, b0.z, b0.w, b1.x, b1.y, b1.z, b1.w};
#pragma unroll
            for (int r = 0; r < 8; ++r)
#pragma unroll
                for (int cc = 0; cc < 8; ++cc)
                    acc[r][cc] = fmaf(ar[r], br[cc], acc[r][cc]);
        }
    }
#pragma unroll
    for (int r = 0; r < 8; ++r) {
        float* Crow = C + (size_t)(m0 + ty * 8 + r) * N + n0 + tx * 8;
#pragma unroll
        for (int cc = 0; cc < 8; ++cc)
            Crow[cc] = acc[r][cc] + (bias ? bias[n0 + tx * 8 + cc] : 0.f);
    }
}

// ---------------- fused LSTM step ----------------
// grid (4 nq, 8 bg), 256 threads. Computes gates = gin_row + h @ Wt, updates h,c.
// gin_row: encoder -> X1 row (b*80 + tstep); decoder -> E2 row sym[b] (biases folded).
__global__ __launch_bounds__(256) void lstm_step(const float* __restrict__ Wt,   // [H][G4]
                                                 const float* __restrict__ gin,
                                                 const int* __restrict__ sym,    // null => encoder
                                                 const float* __restrict__ hin,
                                                 float* __restrict__ hout,
                                                 float* __restrict__ c,
                                                 int tstep) {
    const int nq = blockIdx.x, bg = blockIdx.y;
    const int tid = threadIdx.x;
    const int t = tid >> 6, nl = tid & 63;
    const int j = t * 256 + nq * 64 + nl;
    __shared__ __align__(16) float hs[8][256];
    __shared__ float gs[4][8][64];

    for (int i = tid; i < 8 * 256; i += 256)
        hs[i >> 8][i & 255] = hin[(bg * 8 + (i >> 8)) * 256 + (i & 255)];
    __syncthreads();

    float acc[8] = {0.f, 0.f, 0.f, 0.f, 0.f, 0.f, 0.f, 0.f};
#pragma unroll 8
    for (int k = 0; k < 256; k += 4) {
        float w0 = Wt[(k + 0) * G4 + j];
        float w1 = Wt[(k + 1) * G4 + j];
        float w2 = Wt[(k + 2) * G4 + j];
        float w3 = Wt[(k + 3) * G4 + j];
#pragma unroll
        for (int bl = 0; bl < 8; ++bl) {
            float4 hv = *(const float4*)&hs[bl][k];
            acc[bl] = fmaf(hv.x, w0, acc[bl]);
            acc[bl] = fmaf(hv.y, w1, acc[bl]);
            acc[bl] = fmaf(hv.z, w2, acc[bl]);
            acc[bl] = fmaf(hv.w, w3, acc[bl]);
        }
    }
#pragma unroll
    for (int bl = 0; bl < 8; ++bl) {
        int b = bg * 8 + bl;
        int row = sym ? sym[b] : (b * T_IN + tstep);
        gs[t][bl][nl] = acc[bl] + gin[(size_t)row * G4 + j];
    }
    __syncthreads();

    for (int it = tid; it < 512; it += 256) {
        int bl = it >> 6, n2 = it & 63;
        float gi = gs[0][bl][n2], gf = gs[1][bl][n2];
        float gg = gs[2][bl][n2], go = gs[3][bl][n2];
        float si = 1.f / (1.f + expf(-gi));
        float sf = 1.f / (1.f + expf(-gf));
        float so = 1.f / (1.f + expf(-go));
        int idx = (bg * 8 + bl) * 256 + nq * 64 + n2;
        float cn = sf * c[idx] + si * tanhf(gg);
        c[idx] = cn;
        hout[idx] = so * tanhf(cn);
    }
}

// ---------------- logits + partial argmax ----------------
// grid (24 vb, 8 bg), 256 threads: thread = one v, register-blocked over 8 batch rows.
__global__ __launch_bounds__(256) void logits_step(const float* __restrict__ WoT,  // [H][V]
                                                   const float* __restrict__ b_out,
                                                   const float* __restrict__ h,
                                                   float* __restrict__ out,
                                                   float* __restrict__ pval,
                                                   int* __restrict__ pidx,
                                                   int l) {
    const int vb = blockIdx.x, bg = blockIdx.y;
    const int tid = threadIdx.x;
    const int v = vb * 256 + tid;
    __shared__ __align__(16) float hs[8][256];
    __shared__ float vsh[8][256];

    for (int i = tid; i < 8 * 256; i += 256)
        hs[i >> 8][i & 255] = h[(bg * 8 + (i >> 8)) * 256 + (i & 255)];
    __syncthreads();

    float acc[8] = {0.f, 0.f, 0.f, 0.f, 0.f, 0.f, 0.f, 0.f};
#pragma unroll 8
    for (int k = 0; k < 256; k += 4) {
        float w0 = WoT[(k + 0) * V_SZ + v];
        float w1 = WoT[(k + 1) * V_SZ + v];
        float w2 = WoT[(k + 2) * V_SZ + v];
        float w3 = WoT[(k + 3) * V_SZ + v];
#pragma unroll
        for (int bl = 0; bl < 8; ++bl) {
            float4 hv = *(const float4*)&hs[bl][k];
            acc[bl] = fmaf(hv.x, w0, acc[bl]);
            acc[bl] = fmaf(hv.y, w1, acc[bl]);
            acc[bl] = fmaf(hv.z, w2, acc[bl]);
            acc[bl] = fmaf(hv.w, w3, acc[bl]);
        }
    }
    float bo = b_out[v];
#pragma unroll
    for (int bl = 0; bl < 8; ++bl) {
        float lg = acc[bl] + bo;
        out[((size_t)(bg * 8 + bl) * L_DEC + (l + 1)) * V_SZ + v] = lg;
        vsh[bl][tid] = lg;
    }
    __syncthreads();

    int bl = tid >> 5, lane = tid & 31;
    float best = -INFINITY; int bi = 1 << 30;
    for (int jj = lane; jj < 256; jj += 32) {
        float x = vsh[bl][jj];
        if (x > best) { best = x; bi = jj; }
    }
#pragma unroll
    for (int off = 16; off; off >>= 1) {
        float ov = __shfl_down(best, off, 32);
        int oi = __shfl_down(bi, off, 32);
        if (ov > best || (ov == best && oi < bi)) { best = ov; bi = oi; }
    }
    if (lane == 0) {
        pval[(bg * 8 + bl) * 24 + vb] = best;
        pidx[(bg * 8 + bl) * 24 + vb] = vb * 256 + bi;
    }
}

// ---------------- argmax finalize ----------------
__global__ void argmax_fin(const float* __restrict__ pval, const int* __restrict__ pidx,
                           int* __restrict__ sym, float* __restrict__ out, int l) {
    int b = blockIdx.x, lane = threadIdx.x;  // 32 threads
    float best = -INFINITY; int bi = 1 << 30;
    if (lane < 24) { best = pval[b * 24 + lane]; bi = pidx[b * 24 + lane]; }
#pragma unroll
    for (int off = 16; off; off >>= 1) {
        float ov = __shfl_down(best, off, 32);
        int oi = __shfl_down(bi, off, 32);
        if (ov > best || (ov == best && oi < bi)) { best = ov; bi = oi; }
    }
    if (lane == 0) {
        sym[b] = bi;
        out[SYMBASE + b * L_DEC + (l + 1)] = (float)bi;
    }
}

// ---------------- step-0 outputs: dec_o0 broadcast + SOS symbols ----------------
__global__ void dec0(const float* __restrict__ embed, const float* __restrict__ WoT,
                     const float* __restrict__ b_out, float* __restrict__ out) {
    int v = blockIdx.x * 256 + threadIdx.x;
    __shared__ float es[256];
    es[threadIdx.x] = embed[1 * H_SZ + threadIdx.x];  // SOS = 1
    __syncthreads();
    float acc = 0.f;
#pragma unroll 8
    for (int k = 0; k < 256; ++k) acc = fmaf(es[k], WoT[k * V_SZ + v], acc);
    acc += b_out[v];
    for (int b = 0; b < B_SZ; ++b) out[(size_t)(b * L_DEC) * V_SZ + v] = acc;
    if (blockIdx.x == 0 && threadIdx.x < B_SZ)
        out[SYMBASE + threadIdx.x * L_DEC] = 1.0f;
}

extern "C" void kernel_launch(void* const* d_in, const int* in_sizes, int n_in,
                              void* d_out, int out_size, void* d_ws, size_t ws_size,
                              hipStream_t stream) {
    const float* input = (const float*)d_in[0];
    // d_in[1] target_lengths: all == L_DEC, unused
    const float* embed = (const float*)d_in[2];
    const float* W_out = (const float*)d_in[3];
    const float* b_out = (const float*)d_in[4];
    const float* W_ih1 = (const float*)d_in[5];
    const float* W_hh1 = (const float*)d_in[6];
    const float* b_ih1 = (const float*)d_in[7];
    const float* b_hh1 = (const float*)d_in[8];
    const float* W_ih2 = (const float*)d_in[9];
    const float* W_hh2 = (const float*)d_in[10];
    const float* b_ih2 = (const float*)d_in[11];
    const float* b_hh2 = (const float*)d_in[12];
    float* out = (float*)d_out;

    float* ws = (float*)d_ws;
    float* WhT1 = ws; ws += 256 * 1024;
    float* WhT2 = ws; ws += 256 * 1024;
    float* WoT  = ws; ws += 256 * 6144;
    float* X1   = ws; ws += 5120 * 1024;
    float* E2   = ws; ws += 6144 * 1024;
    float* h0   = ws; ws += 64 * 256;
    float* h1   = ws; ws += 64 * 256;
    float* cbuf = ws; ws += 64 * 256;
    float* bs1  = ws; ws += 1024;
    float* bs2  = ws; ws += 1024;
    float* pval = ws; ws += 64 * 24;
    int* pidx   = (int*)ws; ws += 64 * 24;
    int* symb   = (int*)ws; ws += 64;
    size_t need_bytes = (size_t)((float*)ws - (float*)d_ws) * 4;
    if (ws_size < need_bytes) return;  // scratch too small: fail cleanly

    dim3 tb(32, 8);
    ktranspose<<<dim3(8, 32), tb, 0, stream>>>(W_hh1, WhT1, G4, H_SZ);
    ktranspose<<<dim3(8, 32), tb, 0, stream>>>(W_hh2, WhT2, G4, H_SZ);
    ktranspose<<<dim3(8, 192), tb, 0, stream>>>(W_out, WoT, V_SZ, H_SZ);
    biasum<<<4, 256, 0, stream>>>(b_ih1, b_hh1, b_ih2, b_hh2, bs1, bs2);

    // X1 = input @ W_ih1^T + (b_ih1 + b_hh1) : [5120 x 1024], K=4096
    gemm_rr<<<dim3(8, 40), 256, 0, stream>>>(input, W_ih1, bs1, X1, 5120, 1024, 4096);
    // E2 = embed @ W_ih2^T + (b_ih2 + b_hh2) : [6144 x 1024], K=256
    gemm_rr<<<dim3(8, 48), 256, 0, stream>>>(embed, W_ih2, bs2, E2, 6144, 1024, 256);

    init_state<<<64, 256, 0, stream>>>(h0, cbuf, symb);
    dec0<<<24, 256, 0, stream>>>(embed, WoT, b_out, out);

    // ---- encoder: 80 sequential steps ----
    for (int t = 0; t < T_IN; ++t) {
        const float* hi = (t & 1) ? h1 : h0;
        float* ho = (t & 1) ? h0 : h1;
        lstm_step<<<dim3(4, 8), 256, 0, stream>>>(WhT1, X1, nullptr, hi, ho, cbuf, t);
    }
    // final encoder state ends in h0 (t=79 writes h0)

    // ---- decoder: 29 sequential steps (last computed logits are discarded) ----
    for (int l = 0; l < L_DEC - 1; ++l) {
        const float* hi = (l & 1) ? h1 : h0;
        float* ho = (l & 1) ? h0 : h1;
        lstm_step<<<dim3(4, 8), 256, 0, stream>>>(WhT2, E2, symb, hi, ho, cbuf, 0);
        logits_step<<<dim3(24, 8), 256, 0, stream>>>(WoT, b_out, ho, out, pval, pidx, l);
        argmax_fin<<<64, 32, 0, stream>>>(pval, pidx, symb, out, l);
    }
}